// Round 8
// baseline (476.204 us; speedup 1.0000x reference)
//
#include <hip/hip_runtime.h>
#include <hip/hip_bf16.h>
#include <math.h>

// Problem dims (fixed by reference)
#define BATCH   2
#define SEQ     2048
#define D_MODEL 1024
#define NHEAD   16
#define HEADD   64
#define NROWS   (BATCH * SEQ)   // 4096
#define D_FF    4096
#define TPARTS  4               // attention t-split factor
#define TSPAN   (SEQ / TPARTS)  // 512

typedef __bf16 bf16_t;
typedef __bf16 bf16x2 __attribute__((ext_vector_type(2)));
typedef __bf16 bf16x4 __attribute__((ext_vector_type(4)));
typedef __bf16 bf16x8 __attribute__((ext_vector_type(8)));
typedef float  f32x4  __attribute__((ext_vector_type(4)));

#define QSCALE 0.18033688011112042f   // 0.125 * log2(e), folded into Q

// async global->LDS, 16B per lane, dest = wave-uniform base + lane*16
__device__ __forceinline__ void gload_lds16(const void* g, void* l) {
    __builtin_amdgcn_global_load_lds(
        (const __attribute__((address_space(1))) unsigned int*)g,
        (__attribute__((address_space(3))) unsigned int*)l, 16, 0, 0);
}

// ---------------------------------------------------------------------------
// Weight transpose + fp32 -> bf16:  W[K][N] fp32  ->  Wt[N][K] bf16
// ---------------------------------------------------------------------------
__global__ __launch_bounds__(256) void transpose_to_bf16(
    const float* __restrict__ W, bf16_t* __restrict__ Wt, int K, int N)
{
    __shared__ float tile[32][33];
    int n0 = blockIdx.x * 32;
    int k0 = blockIdx.y * 32;
    int tx = threadIdx.x;   // 0..31
    int ty = threadIdx.y;   // 0..7
    #pragma unroll
    for (int i = 0; i < 32; i += 8)
        tile[ty + i][tx] = W[(size_t)(k0 + ty + i) * N + n0 + tx];
    __syncthreads();
    #pragma unroll
    for (int i = 0; i < 32; i += 8)
        Wt[(size_t)(n0 + ty + i) * K + k0 + tx] = (bf16_t)tile[tx][ty + i];
}

// ---------------------------------------------------------------------------
// LayerNorm: fp32 [rows][1024] -> bf16 [rows][1024].  One block per row.
// ---------------------------------------------------------------------------
__global__ __launch_bounds__(256) void ln_kernel(
    const float* __restrict__ x, const float* __restrict__ g,
    const float* __restrict__ b, bf16_t* __restrict__ out)
{
    int row = blockIdx.x;
    int tid = threadIdx.x;
    const float* xr = x + (size_t)row * D_MODEL;
    f32x4 v = *(const f32x4*)(xr + tid * 4);
    float s  = v[0] + v[1] + v[2] + v[3];
    float s2 = v[0]*v[0] + v[1]*v[1] + v[2]*v[2] + v[3]*v[3];
    #pragma unroll
    for (int off = 32; off; off >>= 1) {
        s  += __shfl_down(s, off);
        s2 += __shfl_down(s2, off);
    }
    __shared__ float ps[4], ps2[4];
    int w = tid >> 6, lane = tid & 63;
    if (lane == 0) { ps[w] = s; ps2[w] = s2; }
    __syncthreads();
    float sum  = ps[0] + ps[1] + ps[2] + ps[3];
    float sum2 = ps2[0] + ps2[1] + ps2[2] + ps2[3];
    float mu  = sum * (1.0f / D_MODEL);
    float var = sum2 * (1.0f / D_MODEL) - mu * mu;
    float rs  = rsqrtf(var + 1e-5f);
    #pragma unroll
    for (int j = 0; j < 4; ++j) {
        int c = tid * 4 + j;
        out[(size_t)row * D_MODEL + c] = (bf16_t)((v[j] - mu) * rs * g[c] + b[c]);
    }
}

// ---------------------------------------------------------------------------
// 128xBN GEMM (m97 structure): C[M][N] = A[M][K](bf16) @ Bt[N][K](bf16)^T.
// BK=32, global_load_lds width=16 staging, unpadded [row][32] LDS.
// 4 waves in 2x2; wave tile 64 x (BN/2) = 4 x (BN/32) MFMA tiles.
// EPI 1: + bias + bf16 residual -> fp32 out (h = xn + y@Wp + bp)
// EPI 2: + bias -> exact GELU -> bf16 out
// EPI 3: + bias + fp32 residual -> fp32 out (final; d_out is float)
// EPI 6: fused QKV: region 0 -> Q*QSCALE scatter [b,h,s,d]; 1 -> K scatter;
//        2 -> V^T packed write [b][h][d][s]   (BN=128 only)
// ---------------------------------------------------------------------------
template<int EPI, int BN>
__global__ __launch_bounds__(256) void gemm128(
    const bf16_t* __restrict__ A, const bf16_t* __restrict__ Bt,
    const float* __restrict__ bias, const void* __restrict__ resid,
    void* __restrict__ out, int M, int N, int K)
{
    constexpr int JN = BN / 32;       // j-tiles per wave
    __shared__ bf16_t As[128 * 32];   // [row][k], 64B rows, no padding
    __shared__ bf16_t Bs[BN * 32];
    int tid = threadIdx.x;
    int m0 = blockIdx.x * 128;
    int n0 = blockIdx.y * BN;
    int w = tid >> 6, lane = tid & 63, quad = lane >> 4, l15 = lane & 15;
    int wm = (w & 1) * 64, wn = (w >> 1) * (BN / 2);
    int srow = tid >> 2;          // 0..63 (staging row, first 64)
    int skg  = (tid & 3) * 8;     // staging k offset

    const bf16_t* Ap = A  + (size_t)(m0 + srow) * K + skg;
    const bf16_t* Bp = Bt + (size_t)(n0 + srow) * K + skg;
    bf16_t* AsW = As + w * 512;   // wave-uniform dest (512 elem = 64 lanes*8)
    bf16_t* BsW = Bs + w * 512;

    f32x4 acc[4][JN] = {};

    for (int k0 = 0; k0 < K; k0 += 32) {
        __syncthreads();                       // prev reads done
        gload_lds16(Ap + k0,                  AsW);
        gload_lds16(Ap + (size_t)64 * K + k0, AsW + 2048);
        gload_lds16(Bp + k0,                  BsW);
        if (BN == 128)
            gload_lds16(Bp + (size_t)64 * K + k0, BsW + 2048);
        __syncthreads();                       // DMA drained (vmcnt0+barrier)
        bf16x8 af[4], bf[JN];
        #pragma unroll
        for (int i = 0; i < 4; ++i)
            af[i] = *(const bf16x8*)&As[(wm + i * 16 + l15) * 32 + quad * 8];
        #pragma unroll
        for (int j = 0; j < JN; ++j)
            bf[j] = *(const bf16x8*)&Bs[(wn + j * 16 + l15) * 32 + quad * 8];
        #pragma unroll
        for (int i = 0; i < 4; ++i)
            #pragma unroll
            for (int j = 0; j < JN; ++j)
                acc[i][j] = __builtin_amdgcn_mfma_f32_16x16x32_bf16(af[i], bf[j], acc[i][j], 0, 0, 0);
    }

    #pragma unroll
    for (int i = 0; i < 4; ++i)
    #pragma unroll
    for (int j = 0; j < JN; ++j) {
        int col  = n0 + wn + j * 16 + l15;
        int row0 = m0 + wm + i * 16 + quad * 4;
        if (EPI == 6) {
            int region = (n0 + wn + j * 16) >> 10;   // 0=Q 1=K 2=V (uniform per j-tile)
            if (region < 2) {
                #pragma unroll
                for (int r = 0; r < 4; ++r) {
                    int row = row0 + r;
                    float v = acc[i][j][r];
                    if (region == 0) v *= QSCALE;
                    int b = row >> 11, s = row & 2047, hh = (col & 1023) >> 6, d = col & 63;
                    bf16_t* dst = (bf16_t*)out + (size_t)region * 4194304;
                    dst[(((size_t)(b * NHEAD + hh)) * SEQ + s) * HEADD + d] = (bf16_t)v;
                }
            } else {
                int dg = col - 2048, hh = dg >> 6, d = dg & 63;
                int b = row0 >> 11, s0 = row0 & 2047;
                bf16x4 pv;
                #pragma unroll
                for (int r = 0; r < 4; ++r) pv[r] = (bf16_t)acc[i][j][r];
                *(bf16x4*)((bf16_t*)out + 8388608
                           + (((size_t)(b * NHEAD + hh)) * HEADD + d) * SEQ + s0) = pv;
            }
        } else {
            float bv = bias[col];
            #pragma unroll
            for (int r = 0; r < 4; ++r) {
                int row = row0 + r;
                float vacc = acc[i][j][r] + bv;
                if (EPI == 1) {
                    float res = (float)((const bf16_t*)resid)[(size_t)row * N + col];
                    ((float*)out)[(size_t)row * N + col] = vacc + res;
                } else if (EPI == 2) {
                    float gl = 0.5f * vacc * (1.0f + erff(vacc * 0.70710678118654752f));
                    ((bf16_t*)out)[(size_t)row * N + col] = (bf16_t)gl;
                } else {
                    float res = ((const float*)resid)[(size_t)row * N + col];
                    ((float*)out)[(size_t)row * N + col] = vacc + res;
                }
            }
        }
    }
}

// ---------------------------------------------------------------------------
// Attention partial kernel.  No-max softmax (Q pre-scaled; exp2 direct) is
// LINEAR in t -> TPARTS=4 t-ranges of 512; partial o (bf16) + partial l.
// R8: TLP over ILP.  No register double-buffer (that cost 64 VGPRs and
// pinned the kernel at 2 waves/SIMD across R4-R7 -- occupancy was register-
// capped, which is why bigger grids didn't help).  __launch_bounds__(256,4)
// forces total regs <= 128 -> 4 waves/SIMD.  Row-sum via ones-column MFMA
// (ls = P @ 1): kills 16 adds/iter + the final shuffle cascade; every lane
// ends up holding the full row sum.
// ---------------------------------------------------------------------------
__global__ __launch_bounds__(256, 4) void attn_kernel(
    const bf16_t* __restrict__ q, const bf16_t* __restrict__ k,
    const bf16_t* __restrict__ vt, bf16_t* __restrict__ po,
    float* __restrict__ plsum)
{
    int gid = blockIdx.x;                 // 0..2047
    int xcd = gid & 7;                    // presumed XCD (any bijection safe)
    int loc = gid >> 3;                   // 0..255
    int bh  = xcd * 4 + (loc >> 6);       // 4 consecutive heads per XCD
    int rest = loc & 63;
    int qt   = rest >> 2;                 // q-tile 0..15
    int part = rest & 3;                  // t-part 0..3
    int tb0 = part * TSPAN, tend = tb0 + TSPAN;
    int b = bh >> 4, h = bh & 15;
    int tid = threadIdx.x, w = tid >> 6, lane = tid & 63;
    int quad = lane >> 4, l15 = lane & 15;
    int qbase = qt * 128 + w * 32;
    const bf16_t* qh = q  + (size_t)bh * SEQ * HEADD;
    const bf16_t* kh = k  + (size_t)bh * SEQ * HEADD;
    const bf16_t* vh = vt + (size_t)bh * HEADD * SEQ;   // [d][t]

    bf16x8 qa[2][2];
    #pragma unroll
    for (int m = 0; m < 2; ++m)
        #pragma unroll
        for (int hf = 0; hf < 2; ++hf)
            qa[m][hf] = *(const bf16x8*)(qh + (size_t)(qbase + m * 16 + l15) * HEADD + hf * 32 + quad * 8);

    bf16x8 ones;
    #pragma unroll
    for (int j = 0; j < 8; ++j) ones[j] = (bf16_t)1.0f;

    __shared__ alignas(16) bf16_t Pl[4][32][40];   // per-wave P (32q x 32t)

    f32x4 o[2][4] = {};
    f32x4 ls[2] = {};

    for (int t0 = tb0; t0 < tend; t0 += 32) {
        bf16x8 kb[2][2], vf[4];
        #pragma unroll
        for (int jt = 0; jt < 2; ++jt)
            #pragma unroll
            for (int hf = 0; hf < 2; ++hf)
                kb[jt][hf] = *(const bf16x8*)(kh + (size_t)(t0 + 2 * l15 + jt) * HEADD + hf * 32 + quad * 8);
        #pragma unroll
        for (int dn = 0; dn < 4; ++dn)
            vf[dn] = *(const bf16x8*)(vh + (size_t)(dn * 16 + l15) * SEQ + t0 + quad * 8);

        #pragma unroll
        for (int m = 0; m < 2; ++m) {
            f32x4 sc[2];
            #pragma unroll
            for (int jt = 0; jt < 2; ++jt) {
                f32x4 z = {};
                z = __builtin_amdgcn_mfma_f32_16x16x32_bf16(qa[m][0], kb[jt][0], z, 0, 0, 0);
                z = __builtin_amdgcn_mfma_f32_16x16x32_bf16(qa[m][1], kb[jt][1], z, 0, 0, 0);
                sc[jt] = z;
            }
            int qm = qbase + m * 16;
            bool dg = (t0 < qm + 16) && (t0 + 32 > qm);  // wave-uniform
            #pragma unroll
            for (int r = 0; r < 4; ++r) {
                int qrow = qm + quad * 4 + r;
                float p0 = __builtin_amdgcn_exp2f(sc[0][r]);
                float p1 = __builtin_amdgcn_exp2f(sc[1][r]);
                if (dg) {
                    int tg = t0 + 2 * l15;
                    if (tg == qrow)     p0 = 0.0f;
                    if (tg + 1 == qrow) p1 = 0.0f;
                }
                bf16x2 pp = { (bf16_t)p0, (bf16_t)p1 };
                *(bf16x2*)&Pl[w][m * 16 + quad * 4 + r][2 * l15] = pp;
            }
        }
        #pragma unroll
        for (int m = 0; m < 2; ++m) {
            bf16x8 pf = *(const bf16x8*)&Pl[w][m * 16 + l15][quad * 8];
            ls[m] = __builtin_amdgcn_mfma_f32_16x16x32_bf16(pf, ones, ls[m], 0, 0, 0);
            #pragma unroll
            for (int dn = 0; dn < 4; ++dn)
                o[m][dn] = __builtin_amdgcn_mfma_f32_16x16x32_bf16(pf, vf[dn], o[m][dn], 0, 0, 0);
        }
    }

    // partial o (bf16, undivided) and partial l (fp32; every lane holds full sum)
    #pragma unroll
    for (int m = 0; m < 2; ++m)
        #pragma unroll
        for (int dn = 0; dn < 4; ++dn)
            #pragma unroll
            for (int r = 0; r < 4; ++r) {
                int qrow = qbase + m * 16 + quad * 4 + r;
                po[(((size_t)part * NROWS) + b * SEQ + qrow) * D_MODEL
                   + h * HEADD + dn * 16 + l15] = (bf16_t)o[m][dn][r];
            }
    if (l15 == 0) {
        #pragma unroll
        for (int m = 0; m < 2; ++m)
            #pragma unroll
            for (int r = 0; r < 4; ++r) {
                int qrow = qbase + m * 16 + quad * 4 + r;
                plsum[((size_t)part * 32 + bh) * SEQ + qrow] = ls[m][r];
            }
    }
}

// ---------------------------------------------------------------------------
// Merge attention partials: y = (sum_p o_p) / (sum_p l_p), bf16 out.
// One block per row (4096 blocks), 256 threads x 4 cols.
// ---------------------------------------------------------------------------
__global__ __launch_bounds__(256) void attn_merge(
    const bf16_t* __restrict__ po, const float* __restrict__ plsum,
    bf16_t* __restrict__ y)
{
    int row = blockIdx.x;
    int tid = threadIdx.x;
    int c = tid * 4;
    int b = row >> 11, s = row & 2047;
    int bh = b * NHEAD + (c >> 6);
    float l = 0.0f;
    f32x4 ov = {};
    #pragma unroll
    for (int p = 0; p < TPARTS; ++p) {
        l += plsum[((size_t)p * 32 + bh) * SEQ + s];
        bf16x4 t = *(const bf16x4*)&po[((size_t)p * NROWS + row) * D_MODEL + c];
        #pragma unroll
        for (int j = 0; j < 4; ++j) ov[j] += (float)t[j];
    }
    float rl = 1.0f / l;
    bf16x4 out;
    #pragma unroll
    for (int j = 0; j < 4; ++j) out[j] = (bf16_t)(ov[j] * rl);
    *(bf16x4*)&y[(size_t)row * D_MODEL + c] = out;
}

// ---------------------------------------------------------------------------
extern "C" void kernel_launch(void* const* d_in, const int* in_sizes, int n_in,
                              void* d_out, int out_size, void* d_ws, size_t ws_size,
                              hipStream_t stream)
{
    const float* x   = (const float*)d_in[0];
    const float* Wk  = (const float*)d_in[1];
    const float* Wq  = (const float*)d_in[2];
    const float* Wv  = (const float*)d_in[3];
    const float* Wp  = (const float*)d_in[4];
    const float* bp  = (const float*)d_in[5];
    const float* g1  = (const float*)d_in[6];
    const float* b1  = (const float*)d_in[7];
    const float* g2  = (const float*)d_in[8];
    const float* b2  = (const float*)d_in[9];
    const float* W1  = (const float*)d_in[10];
    const float* bm1 = (const float*)d_in[11];
    const float* W2  = (const float*)d_in[12];
    const float* bm2 = (const float*)d_in[13];

    char* ws = (char*)d_ws;
    const size_t MB = 1024 * 1024;
    bf16_t* Wqkvt = (bf16_t*)(ws + 0 * MB);  // 6MB [3072][1024]: Q^T|K^T|V^T
    bf16_t* Wpt = (bf16_t*)(ws + 6 * MB);    // 2MB
    bf16_t* W1t = (bf16_t*)(ws + 8 * MB);    // 8MB  [4096][1024]
    bf16_t* W2t = (bf16_t*)(ws + 16 * MB);   // 8MB  [1024][4096]
    bf16_t* xn  = (bf16_t*)(ws + 24 * MB);   // 8MB (live until proj residual)
    bf16_t* qkv = (bf16_t*)(ws + 32 * MB);   // fused QKV out base (24MB)
    bf16_t* qb  = (bf16_t*)(ws + 32 * MB);   // 8MB [b][h][s][d], Q pre-scaled
    bf16_t* kb  = (bf16_t*)(ws + 40 * MB);   // 8MB [b][h][s][d]
    bf16_t* vtb = (bf16_t*)(ws + 48 * MB);   // 8MB [b][h][d][s]
    bf16_t* yb  = (bf16_t*)(ws + 56 * MB);   // 8MB merged attn out
    float*  hbuf= (float*) (ws + 64 * MB);   // 16MB fp32 (written after merge)
    bf16_t* po  = (bf16_t*)(ws + 64 * MB);   // 32MB attn partials (dead at proj)
    float*  pls = (float*) (ws + 96 * MB);   // 1MB  lsum partials
    bf16_t* hn  = (bf16_t*)(ws + 24 * MB);   // reuse xn slot (xn dead by then)
    bf16_t* act = (bf16_t*)(ws + 32 * MB);   // 32MB, reuses qkv region

    dim3 tb(32, 8);
    transpose_to_bf16<<<dim3(32, 32), tb, 0, stream>>>(Wq, Wqkvt,               1024, 1024);
    transpose_to_bf16<<<dim3(32, 32), tb, 0, stream>>>(Wk, Wqkvt + 1024 * 1024, 1024, 1024);
    transpose_to_bf16<<<dim3(32, 32), tb, 0, stream>>>(Wv, Wqkvt + 2048 * 1024, 1024, 1024);
    transpose_to_bf16<<<dim3(32, 32), tb, 0, stream>>>(Wp, Wpt, 1024, 1024);
    transpose_to_bf16<<<dim3(128, 32), tb, 0, stream>>>(W1, W1t, 1024, 4096);
    transpose_to_bf16<<<dim3(32, 128), tb, 0, stream>>>(W2, W2t, 4096, 1024);

    ln_kernel<<<NROWS, 256, 0, stream>>>(x, g1, b1, xn);

    // fused QKV projection: N = 3072, epilogue scatters Q (scaled), K, V^T
    gemm128<6, 128><<<dim3(32, 24), 256, 0, stream>>>(xn, Wqkvt, nullptr, nullptr, qkv, NROWS, 3072, D_MODEL);

    attn_kernel<<<2048, 256, 0, stream>>>(qb, kb, vtb, po, pls);
    attn_merge<<<NROWS, 256, 0, stream>>>(po, pls, yb);

    gemm128<1, 64><<<dim3(32, 16), 256, 0, stream>>>(yb, Wpt, bp, xn, hbuf, NROWS, D_MODEL, D_MODEL);

    ln_kernel<<<NROWS, 256, 0, stream>>>(hbuf, g2, b2, hn);

    gemm128<2, 128><<<dim3(32, 32), 256, 0, stream>>>(hn, W1t, bm1, nullptr, act, NROWS, D_FF, D_MODEL);
    gemm128<3, 64><<<dim3(32, 16), 256, 0, stream>>>(act, W2t, bm2, hbuf, d_out, NROWS, D_MODEL, D_FF);
}

// Round 9
// 403.741 us; speedup vs baseline: 1.1795x; 1.1795x over previous
//
#include <hip/hip_runtime.h>
#include <hip/hip_bf16.h>
#include <math.h>

// Problem dims (fixed by reference)
#define BATCH   2
#define SEQ     2048
#define D_MODEL 1024
#define NHEAD   16
#define HEADD   64
#define NROWS   (BATCH * SEQ)   // 4096
#define D_FF    4096
#define TPARTS  4               // attention t-split factor
#define TSPAN   (SEQ / TPARTS)  // 512

typedef __bf16 bf16_t;
typedef __bf16 bf16x2 __attribute__((ext_vector_type(2)));
typedef __bf16 bf16x4 __attribute__((ext_vector_type(4)));
typedef __bf16 bf16x8 __attribute__((ext_vector_type(8)));
typedef float  f32x4  __attribute__((ext_vector_type(4)));

#define QSCALE 0.18033688011112042f   // 0.125 * log2(e), folded into Q

// async global->LDS, 16B per lane, dest = wave-uniform base + lane*16
__device__ __forceinline__ void gload_lds16(const void* g, void* l) {
    __builtin_amdgcn_global_load_lds(
        (const __attribute__((address_space(1))) unsigned int*)g,
        (__attribute__((address_space(3))) unsigned int*)l, 16, 0, 0);
}

// ---------------------------------------------------------------------------
// Weight transpose + fp32 -> bf16:  W[K][N] fp32  ->  Wt[N][K] bf16
// ---------------------------------------------------------------------------
__global__ __launch_bounds__(256) void transpose_to_bf16(
    const float* __restrict__ W, bf16_t* __restrict__ Wt, int K, int N)
{
    __shared__ float tile[32][33];
    int n0 = blockIdx.x * 32;
    int k0 = blockIdx.y * 32;
    int tx = threadIdx.x;   // 0..31
    int ty = threadIdx.y;   // 0..7
    #pragma unroll
    for (int i = 0; i < 32; i += 8)
        tile[ty + i][tx] = W[(size_t)(k0 + ty + i) * N + n0 + tx];
    __syncthreads();
    #pragma unroll
    for (int i = 0; i < 32; i += 8)
        Wt[(size_t)(n0 + ty + i) * K + k0 + tx] = (bf16_t)tile[tx][ty + i];
}

// ---------------------------------------------------------------------------
// LayerNorm: fp32 [rows][1024] -> bf16 [rows][1024].  One block per row.
// ---------------------------------------------------------------------------
__global__ __launch_bounds__(256) void ln_kernel(
    const float* __restrict__ x, const float* __restrict__ g,
    const float* __restrict__ b, bf16_t* __restrict__ out)
{
    int row = blockIdx.x;
    int tid = threadIdx.x;
    const float* xr = x + (size_t)row * D_MODEL;
    f32x4 v = *(const f32x4*)(xr + tid * 4);
    float s  = v[0] + v[1] + v[2] + v[3];
    float s2 = v[0]*v[0] + v[1]*v[1] + v[2]*v[2] + v[3]*v[3];
    #pragma unroll
    for (int off = 32; off; off >>= 1) {
        s  += __shfl_down(s, off);
        s2 += __shfl_down(s2, off);
    }
    __shared__ float ps[4], ps2[4];
    int w = tid >> 6, lane = tid & 63;
    if (lane == 0) { ps[w] = s; ps2[w] = s2; }
    __syncthreads();
    float sum  = ps[0] + ps[1] + ps[2] + ps[3];
    float sum2 = ps2[0] + ps2[1] + ps2[2] + ps2[3];
    float mu  = sum * (1.0f / D_MODEL);
    float var = sum2 * (1.0f / D_MODEL) - mu * mu;
    float rs  = rsqrtf(var + 1e-5f);
    #pragma unroll
    for (int j = 0; j < 4; ++j) {
        int c = tid * 4 + j;
        out[(size_t)row * D_MODEL + c] = (bf16_t)((v[j] - mu) * rs * g[c] + b[c]);
    }
}

// ---------------------------------------------------------------------------
// 128xBN GEMM (m97 structure): C[M][N] = A[M][K](bf16) @ Bt[N][K](bf16)^T.
// BK=32, global_load_lds width=16 staging, unpadded [row][32] LDS.
// 4 waves in 2x2; wave tile 64 x (BN/2) = 4 x (BN/32) MFMA tiles.
// EPI 1: + bias + bf16 residual -> fp32 out (h = xn + y@Wp + bp)
// EPI 2: + bias -> exact GELU -> bf16 out
// EPI 3: + bias + fp32 residual -> fp32 out (final; d_out is float)
// EPI 6: fused QKV: region 0 -> Q*QSCALE scatter [b,h,s,d]; 1 -> K scatter;
//        2 -> V^T packed write [b][h][d][s]   (BN=128 only)
// ---------------------------------------------------------------------------
template<int EPI, int BN>
__global__ __launch_bounds__(256) void gemm128(
    const bf16_t* __restrict__ A, const bf16_t* __restrict__ Bt,
    const float* __restrict__ bias, const void* __restrict__ resid,
    void* __restrict__ out, int M, int N, int K)
{
    constexpr int JN = BN / 32;       // j-tiles per wave
    __shared__ bf16_t As[128 * 32];   // [row][k], 64B rows, no padding
    __shared__ bf16_t Bs[BN * 32];
    int tid = threadIdx.x;
    int m0 = blockIdx.x * 128;
    int n0 = blockIdx.y * BN;
    int w = tid >> 6, lane = tid & 63, quad = lane >> 4, l15 = lane & 15;
    int wm = (w & 1) * 64, wn = (w >> 1) * (BN / 2);
    int srow = tid >> 2;          // 0..63 (staging row, first 64)
    int skg  = (tid & 3) * 8;     // staging k offset

    const bf16_t* Ap = A  + (size_t)(m0 + srow) * K + skg;
    const bf16_t* Bp = Bt + (size_t)(n0 + srow) * K + skg;
    bf16_t* AsW = As + w * 512;   // wave-uniform dest (512 elem = 64 lanes*8)
    bf16_t* BsW = Bs + w * 512;

    f32x4 acc[4][JN] = {};

    for (int k0 = 0; k0 < K; k0 += 32) {
        __syncthreads();                       // prev reads done
        gload_lds16(Ap + k0,                  AsW);
        gload_lds16(Ap + (size_t)64 * K + k0, AsW + 2048);
        gload_lds16(Bp + k0,                  BsW);
        if (BN == 128)
            gload_lds16(Bp + (size_t)64 * K + k0, BsW + 2048);
        __syncthreads();                       // DMA drained (vmcnt0+barrier)
        bf16x8 af[4], bf[JN];
        #pragma unroll
        for (int i = 0; i < 4; ++i)
            af[i] = *(const bf16x8*)&As[(wm + i * 16 + l15) * 32 + quad * 8];
        #pragma unroll
        for (int j = 0; j < JN; ++j)
            bf[j] = *(const bf16x8*)&Bs[(wn + j * 16 + l15) * 32 + quad * 8];
        #pragma unroll
        for (int i = 0; i < 4; ++i)
            #pragma unroll
            for (int j = 0; j < JN; ++j)
                acc[i][j] = __builtin_amdgcn_mfma_f32_16x16x32_bf16(af[i], bf[j], acc[i][j], 0, 0, 0);
    }

    #pragma unroll
    for (int i = 0; i < 4; ++i)
    #pragma unroll
    for (int j = 0; j < JN; ++j) {
        int col  = n0 + wn + j * 16 + l15;
        int row0 = m0 + wm + i * 16 + quad * 4;
        if (EPI == 6) {
            int region = (n0 + wn + j * 16) >> 10;   // 0=Q 1=K 2=V (uniform per j-tile)
            if (region < 2) {
                #pragma unroll
                for (int r = 0; r < 4; ++r) {
                    int row = row0 + r;
                    float v = acc[i][j][r];
                    if (region == 0) v *= QSCALE;
                    int b = row >> 11, s = row & 2047, hh = (col & 1023) >> 6, d = col & 63;
                    bf16_t* dst = (bf16_t*)out + (size_t)region * 4194304;
                    dst[(((size_t)(b * NHEAD + hh)) * SEQ + s) * HEADD + d] = (bf16_t)v;
                }
            } else {
                int dg = col - 2048, hh = dg >> 6, d = dg & 63;
                int b = row0 >> 11, s0 = row0 & 2047;
                bf16x4 pv;
                #pragma unroll
                for (int r = 0; r < 4; ++r) pv[r] = (bf16_t)acc[i][j][r];
                *(bf16x4*)((bf16_t*)out + 8388608
                           + (((size_t)(b * NHEAD + hh)) * HEADD + d) * SEQ + s0) = pv;
            }
        } else {
            float bv = bias[col];
            #pragma unroll
            for (int r = 0; r < 4; ++r) {
                int row = row0 + r;
                float vacc = acc[i][j][r] + bv;
                if (EPI == 1) {
                    float res = (float)((const bf16_t*)resid)[(size_t)row * N + col];
                    ((float*)out)[(size_t)row * N + col] = vacc + res;
                } else if (EPI == 2) {
                    float gl = 0.5f * vacc * (1.0f + erff(vacc * 0.70710678118654752f));
                    ((bf16_t*)out)[(size_t)row * N + col] = (bf16_t)gl;
                } else {
                    float res = ((const float*)resid)[(size_t)row * N + col];
                    ((float*)out)[(size_t)row * N + col] = vacc + res;
                }
            }
        }
    }
}

// ---------------------------------------------------------------------------
// Attention partial kernel.  No-max softmax (Q pre-scaled; exp2 direct) is
// LINEAR in t -> TPARTS=4 t-ranges of 512; partial o (bf16) + partial l.
// R9: the R4-R8 fragment loads were 16-cache-line gathers (l15 stride 256B/
// 4KB), 8 per iter per wave, duplicated across the block's 4 waves -- a
// per-CU TA/TCP request wall invisible to MfmaUtil/VALU/occupancy counters
// (all four neutral rounds).  Now: K-tile (32t x 64d) and Vt-tile (64d x 32t)
// are staged cooperatively per block with fully-coalesced b128 loads (each
// line fetched once per block), m97-style 2-barrier loop; fragments read
// from LDS.  Padded rows (72/40 elems) avoid the 16-way l15-vanishing bank
// pattern; b128 ops run at the 128B/clk LDS floor.
// ---------------------------------------------------------------------------
__global__ __launch_bounds__(256, 4) void attn_kernel(
    const bf16_t* __restrict__ q, const bf16_t* __restrict__ k,
    const bf16_t* __restrict__ vt, bf16_t* __restrict__ po,
    float* __restrict__ plsum)
{
    int gid = blockIdx.x;                 // 0..2047
    int xcd = gid & 7;                    // presumed XCD (any bijection safe)
    int loc = gid >> 3;                   // 0..255
    int bh  = xcd * 4 + (loc >> 6);       // 4 consecutive heads per XCD
    int rest = loc & 63;
    int qt   = rest >> 2;                 // q-tile 0..15
    int part = rest & 3;                  // t-part 0..3
    int tb0 = part * TSPAN, tend = tb0 + TSPAN;
    int b = bh >> 4, h = bh & 15;
    int tid = threadIdx.x, w = tid >> 6, lane = tid & 63;
    int quad = lane >> 4, l15 = lane & 15;
    int qbase = qt * 128 + w * 32;
    const bf16_t* qh = q  + (size_t)bh * SEQ * HEADD;
    const bf16_t* kh = k  + (size_t)bh * SEQ * HEADD;
    const bf16_t* vh = vt + (size_t)bh * HEADD * SEQ;   // [d][t]

    bf16x8 qa[2][2];
    #pragma unroll
    for (int m = 0; m < 2; ++m)
        #pragma unroll
        for (int hf = 0; hf < 2; ++hf)
            qa[m][hf] = *(const bf16x8*)(qh + (size_t)(qbase + m * 16 + l15) * HEADD + hf * 32 + quad * 8);

    bf16x8 ones;
    #pragma unroll
    for (int j = 0; j < 8; ++j) ones[j] = (bf16_t)1.0f;

    __shared__ alignas(16) bf16_t Ks[32 * 72];     // [t][d], rows padded to 72
    __shared__ alignas(16) bf16_t Vs[64 * 40];     // [d][t], rows padded to 40
    __shared__ alignas(16) bf16_t Pl[4][32][40];   // per-wave P (32q x 32t)

    // staging indices: K tile is 4KB contiguous; V tile is 64 rows x 64B
    int ksrow = tid >> 3, kscol = (tid & 7) * 8;   // t-row, d-chunk
    int vsrow = tid >> 2, vscol = (tid & 3) * 8;   // d-row, t-chunk
    const bf16_t* kg = kh + (size_t)ksrow * HEADD + kscol;
    const bf16_t* vg = vh + (size_t)vsrow * SEQ + vscol;

    f32x4 o[2][4] = {};
    f32x4 ls[2] = {};

    for (int t0 = tb0; t0 < tend; t0 += 32) {
        bf16x8 kreg = *(const bf16x8*)(kg + (size_t)t0 * HEADD);
        bf16x8 vreg = *(const bf16x8*)(vg + t0);
        __syncthreads();                           // prev-iter readers done
        *(bf16x8*)&Ks[ksrow * 72 + kscol] = kreg;
        *(bf16x8*)&Vs[vsrow * 40 + vscol] = vreg;
        __syncthreads();                           // tiles visible

        bf16x8 kb[2][2], vf[4];
        #pragma unroll
        for (int jt = 0; jt < 2; ++jt)
            #pragma unroll
            for (int hf = 0; hf < 2; ++hf)
                kb[jt][hf] = *(const bf16x8*)&Ks[(2 * l15 + jt) * 72 + hf * 32 + quad * 8];
        #pragma unroll
        for (int dn = 0; dn < 4; ++dn)
            vf[dn] = *(const bf16x8*)&Vs[(dn * 16 + l15) * 40 + quad * 8];

        #pragma unroll
        for (int m = 0; m < 2; ++m) {
            f32x4 sc[2];
            #pragma unroll
            for (int jt = 0; jt < 2; ++jt) {
                f32x4 z = {};
                z = __builtin_amdgcn_mfma_f32_16x16x32_bf16(qa[m][0], kb[jt][0], z, 0, 0, 0);
                z = __builtin_amdgcn_mfma_f32_16x16x32_bf16(qa[m][1], kb[jt][1], z, 0, 0, 0);
                sc[jt] = z;
            }
            int qm = qbase + m * 16;
            bool dg = (t0 < qm + 16) && (t0 + 32 > qm);  // wave-uniform
            #pragma unroll
            for (int r = 0; r < 4; ++r) {
                int qrow = qm + quad * 4 + r;
                float p0 = __builtin_amdgcn_exp2f(sc[0][r]);
                float p1 = __builtin_amdgcn_exp2f(sc[1][r]);
                if (dg) {
                    int tg = t0 + 2 * l15;
                    if (tg == qrow)     p0 = 0.0f;
                    if (tg + 1 == qrow) p1 = 0.0f;
                }
                bf16x2 pp = { (bf16_t)p0, (bf16_t)p1 };
                *(bf16x2*)&Pl[w][m * 16 + quad * 4 + r][2 * l15] = pp;
            }
        }
        #pragma unroll
        for (int m = 0; m < 2; ++m) {
            bf16x8 pf = *(const bf16x8*)&Pl[w][m * 16 + l15][quad * 8];
            ls[m] = __builtin_amdgcn_mfma_f32_16x16x32_bf16(pf, ones, ls[m], 0, 0, 0);
            #pragma unroll
            for (int dn = 0; dn < 4; ++dn)
                o[m][dn] = __builtin_amdgcn_mfma_f32_16x16x32_bf16(pf, vf[dn], o[m][dn], 0, 0, 0);
        }
    }

    // partial o (bf16, undivided) and partial l (fp32; every lane holds full sum)
    #pragma unroll
    for (int m = 0; m < 2; ++m)
        #pragma unroll
        for (int dn = 0; dn < 4; ++dn)
            #pragma unroll
            for (int r = 0; r < 4; ++r) {
                int qrow = qbase + m * 16 + quad * 4 + r;
                po[(((size_t)part * NROWS) + b * SEQ + qrow) * D_MODEL
                   + h * HEADD + dn * 16 + l15] = (bf16_t)o[m][dn][r];
            }
    if (l15 == 0) {
        #pragma unroll
        for (int m = 0; m < 2; ++m)
            #pragma unroll
            for (int r = 0; r < 4; ++r) {
                int qrow = qbase + m * 16 + quad * 4 + r;
                plsum[((size_t)part * 32 + bh) * SEQ + qrow] = ls[m][r];
            }
    }
}

// ---------------------------------------------------------------------------
// Merge attention partials: y = (sum_p o_p) / (sum_p l_p), bf16 out.
// One block per row (4096 blocks), 256 threads x 4 cols.
// ---------------------------------------------------------------------------
__global__ __launch_bounds__(256) void attn_merge(
    const bf16_t* __restrict__ po, const float* __restrict__ plsum,
    bf16_t* __restrict__ y)
{
    int row = blockIdx.x;
    int tid = threadIdx.x;
    int c = tid * 4;
    int b = row >> 11, s = row & 2047;
    int bh = b * NHEAD + (c >> 6);
    float l = 0.0f;
    f32x4 ov = {};
    #pragma unroll
    for (int p = 0; p < TPARTS; ++p) {
        l += plsum[((size_t)p * 32 + bh) * SEQ + s];
        bf16x4 t = *(const bf16x4*)&po[((size_t)p * NROWS + row) * D_MODEL + c];
        #pragma unroll
        for (int j = 0; j < 4; ++j) ov[j] += (float)t[j];
    }
    float rl = 1.0f / l;
    bf16x4 out;
    #pragma unroll
    for (int j = 0; j < 4; ++j) out[j] = (bf16_t)(ov[j] * rl);
    *(bf16x4*)&y[(size_t)row * D_MODEL + c] = out;
}

// ---------------------------------------------------------------------------
extern "C" void kernel_launch(void* const* d_in, const int* in_sizes, int n_in,
                              void* d_out, int out_size, void* d_ws, size_t ws_size,
                              hipStream_t stream)
{
    const float* x   = (const float*)d_in[0];
    const float* Wk  = (const float*)d_in[1];
    const float* Wq  = (const float*)d_in[2];
    const float* Wv  = (const float*)d_in[3];
    const float* Wp  = (const float*)d_in[4];
    const float* bp  = (const float*)d_in[5];
    const float* g1  = (const float*)d_in[6];
    const float* b1  = (const float*)d_in[7];
    const float* g2  = (const float*)d_in[8];
    const float* b2  = (const float*)d_in[9];
    const float* W1  = (const float*)d_in[10];
    const float* bm1 = (const float*)d_in[11];
    const float* W2  = (const float*)d_in[12];
    const float* bm2 = (const float*)d_in[13];

    char* ws = (char*)d_ws;
    const size_t MB = 1024 * 1024;
    bf16_t* Wqkvt = (bf16_t*)(ws + 0 * MB);  // 6MB [3072][1024]: Q^T|K^T|V^T
    bf16_t* Wpt = (bf16_t*)(ws + 6 * MB);    // 2MB
    bf16_t* W1t = (bf16_t*)(ws + 8 * MB);    // 8MB  [4096][1024]
    bf16_t* W2t = (bf16_t*)(ws + 16 * MB);   // 8MB  [1024][4096]
    bf16_t* xn  = (bf16_t*)(ws + 24 * MB);   // 8MB (live until proj residual)
    bf16_t* qkv = (bf16_t*)(ws + 32 * MB);   // fused QKV out base (24MB)
    bf16_t* qb  = (bf16_t*)(ws + 32 * MB);   // 8MB [b][h][s][d], Q pre-scaled
    bf16_t* kb  = (bf16_t*)(ws + 40 * MB);   // 8MB [b][h][s][d]
    bf16_t* vtb = (bf16_t*)(ws + 48 * MB);   // 8MB [b][h][d][s]
    bf16_t* yb  = (bf16_t*)(ws + 56 * MB);   // 8MB merged attn out
    float*  hbuf= (float*) (ws + 64 * MB);   // 16MB fp32 (written after merge)
    bf16_t* po  = (bf16_t*)(ws + 64 * MB);   // 32MB attn partials (dead at proj)
    float*  pls = (float*) (ws + 96 * MB);   // 1MB  lsum partials
    bf16_t* hn  = (bf16_t*)(ws + 24 * MB);   // reuse xn slot (xn dead by then)
    bf16_t* act = (bf16_t*)(ws + 32 * MB);   // 32MB, reuses qkv region

    dim3 tb(32, 8);
    transpose_to_bf16<<<dim3(32, 32), tb, 0, stream>>>(Wq, Wqkvt,               1024, 1024);
    transpose_to_bf16<<<dim3(32, 32), tb, 0, stream>>>(Wk, Wqkvt + 1024 * 1024, 1024, 1024);
    transpose_to_bf16<<<dim3(32, 32), tb, 0, stream>>>(Wv, Wqkvt + 2048 * 1024, 1024, 1024);
    transpose_to_bf16<<<dim3(32, 32), tb, 0, stream>>>(Wp, Wpt, 1024, 1024);
    transpose_to_bf16<<<dim3(128, 32), tb, 0, stream>>>(W1, W1t, 1024, 4096);
    transpose_to_bf16<<<dim3(32, 128), tb, 0, stream>>>(W2, W2t, 4096, 1024);

    ln_kernel<<<NROWS, 256, 0, stream>>>(x, g1, b1, xn);

    // fused QKV projection: N = 3072, epilogue scatters Q (scaled), K, V^T
    gemm128<6, 128><<<dim3(32, 24), 256, 0, stream>>>(xn, Wqkvt, nullptr, nullptr, qkv, NROWS, 3072, D_MODEL);

    attn_kernel<<<2048, 256, 0, stream>>>(qb, kb, vtb, po, pls);
    attn_merge<<<NROWS, 256, 0, stream>>>(po, pls, yb);

    gemm128<1, 64><<<dim3(32, 16), 256, 0, stream>>>(yb, Wpt, bp, xn, hbuf, NROWS, D_MODEL, D_MODEL);

    ln_kernel<<<NROWS, 256, 0, stream>>>(hbuf, g2, b2, hn);

    gemm128<2, 128><<<dim3(32, 32), 256, 0, stream>>>(hn, W1t, bm1, nullptr, act, NROWS, D_FF, D_MODEL);
    gemm128<3, 64><<<dim3(32, 16), 256, 0, stream>>>(act, W2t, bm2, hbuf, d_out, NROWS, D_MODEL, D_FF);
}